// Round 5
// baseline (30.671 us; speedup 1.0000x reference)
//
#include <hip/hip_runtime.h>

#define S_LEN 4096
#define DIM   64
#define HALF  50
#define RB    256           // query rows per block
#define WQ    16            // query rows per wave (16 waves)
#define THREADS 1024
#define KCAP  384           // staged keys: kstart = r0-64 (aligned), span <= 370
#define CHUNK 128           // keys per staging chunk = 4 tiles of 32
#define NCH   3
#define SCALE 0.125f

typedef __attribute__((ext_vector_type(8))) short bf16x8;
typedef __attribute__((ext_vector_type(4))) float f32x4;

__device__ __forceinline__ unsigned int bf16_rne(float f) {
    unsigned int u = __float_as_uint(f);
    return (u + 0x7fffu + ((u >> 16) & 1u)) >> 16;
}
__device__ __forceinline__ unsigned int pk2(float lo, float hi) {
    return bf16_rne(lo) | (bf16_rne(hi) << 16);
}

// LDS: K  [384 keys][64 d] bf16, slot' = slot ^ (key&7)                (48KB)
//      V^T[64 d][384 keys] bf16, slot' = slot ^ (d&7)                  (48KB)
//      P  [16 waves][16 q][40 k] bf16 per-wave scratch                 (20KB)
// 116KB -> 1 block/CU; overlap comes from 3-chunk pipelined staging:
//   load(c+1)->regs | compute tiles of chunk c | convert+write(c+1) | barrier
__global__ __launch_bounds__(THREADS)
void lattn_mfma(const float* __restrict__ Q, const float* __restrict__ K,
                const float* __restrict__ V, float* __restrict__ O) {
    __shared__ unsigned short Ks[KCAP * 64];
    __shared__ unsigned short Vs[DIM * KCAP];
    __shared__ unsigned short Ps[16 * 16 * 40];

    // bijective XCD swizzle: consecutive r0-blocks (overlapping halos) share an XCD L2
    const int nwg = gridDim.x;                 // 256
    const int cpx = nwg >> 3;
    const int bid = blockIdx.x;
    const int logical = (bid & 7) * cpx + (bid >> 3);
    const int bh = logical >> 4;               // 16 x-blocks per bh
    const int r0 = (logical & 15) * RB;

    const size_t base = (size_t)bh * (S_LEN * DIM);
    const float* Qg = Q + base;
    const float* Kg = K + base;
    const float* Vg = V + base;
    float*       Og = O + base;

    const int kstart = (r0 >= HALF) ? ((r0 - HALF) & ~31) : 0;
    const int kend   = min(S_LEN, r0 + RB + HALF);   // exclusive
    const int nkeys  = ((kend - kstart + 31) >> 5) << 5;   // 320 or 384

    const int u = threadIdx.x;

    // ---- staging helpers (K: 1024 threads x 1 row-octet; V: 512 threads x key-pair) ----
    auto k_load = [&](int c, float4& a, float4& b) {
        const int kg  = kstart + c * CHUNK + (u >> 3);
        const int oct = u & 7;
        if (kg < kend) {
            a = *(const float4*)(Kg + (size_t)kg * DIM + oct * 8);
            b = *(const float4*)(Kg + (size_t)kg * DIM + oct * 8 + 4);
        } else {
            a = make_float4(0.f, 0.f, 0.f, 0.f); b = a;
        }
    };
    auto k_write = [&](int c, float4 a, float4 b) {
        const int krow = c * CHUNK + (u >> 3);
        const int oct  = u & 7;
        *(uint4*)(Ks + krow * 64 + ((oct ^ (krow & 7)) << 3)) =
            make_uint4(pk2(a.x, a.y), pk2(a.z, a.w), pk2(b.x, b.y), pk2(b.z, b.w));
    };
    auto v_load = [&](int c, float4* r) {
        if (u < 512) {
            const int kg = kstart + c * CHUNK + (u >> 3) * 2;
            const int d0 = (u & 7) * 8;
            if (kg < kend) {
                const float* va = Vg + (size_t)kg * DIM + d0;
                r[0] = *(const float4*)va;       r[1] = *(const float4*)(va + 4);
                r[2] = *(const float4*)(va + DIM); r[3] = *(const float4*)(va + DIM + 4);
            } else {
                r[0] = make_float4(0.f, 0.f, 0.f, 0.f); r[1] = r[0]; r[2] = r[0]; r[3] = r[0];
            }
        }
    };
    auto v_write = [&](int c, const float4* r) {
        if (u < 512) {
            const int k0 = c * CHUNK + (u >> 3) * 2;
            const int m  = u & 7;
            const float* a0 = (const float*)r;        // key k0
            const float* a1 = (const float*)(r + 2);  // key k0+1
            #pragma unroll
            for (int j = 0; j < 8; ++j) {
                const int jj = (j + m) & 7;           // rotate: 8 sharers hit 8 banks
                const int d  = m * 8 + jj;
                const int sl = (k0 >> 3) ^ (d & 7);
                *(unsigned int*)(Vs + d * KCAP + sl * 8 + (k0 & 7)) = pk2(a0[jj], a1[jj]);
            }
        }
    };

    // ---- prologue: stage chunk 0 directly; Q^T B-fragments from global ----
    {
        float4 ka, kb, vr[4];
        k_load(0, ka, kb); v_load(0, vr);
        k_write(0, ka, kb); v_write(0, vr);
    }

    const int lane = u & 63;
    const int wv_  = u >> 6;
    const int g  = lane >> 4;
    const int cc = lane & 15;
    const int qlo = r0 + WQ * wv_;

    bf16x8 qf[2];
    #pragma unroll
    for (int ds = 0; ds < 2; ++ds) {
        const float* src = Qg + (size_t)(qlo + cc) * DIM + ds * 32 + g * 8;
        const float4 a = *(const float4*)src;
        const float4 b = *(const float4*)(src + 4);
        uint4 t = make_uint4(pk2(a.x * SCALE, a.y * SCALE), pk2(a.z * SCALE, a.w * SCALE),
                             pk2(b.x * SCALE, b.y * SCALE), pk2(b.z * SCALE, b.w * SCALE));
        qf[ds] = __builtin_bit_cast(bf16x8, t);
    }

    __syncthreads();

    f32x4 oacc[4] = {};
    float denom = 0.f;

    // per-wave tile range
    int lo = (qlo >= HALF) ? (qlo - HALF) : 0;
    lo = max(kstart, lo & ~31);
    const int t0 = (lo - kstart) >> 5;
    const int hi = min(kend, qlo + WQ - 1 + HALF + 1);
    const int t1 = (hi - kstart + 31) >> 5;

    unsigned short* Pw = Ps + wv_ * (16 * 40);

    for (int c = 0; c < NCH; ++c) {
        // 1) issue next chunk's global loads (latency hides under compute below)
        float4 ka, kb, vr[4];
        const bool more = (c + 1 < NCH) && ((c + 1) * CHUNK < nkeys);
        if (more) { k_load(c + 1, ka, kb); v_load(c + 1, vr); }

        // 2) compute this wave's tiles inside chunk c
        const int sa = max(t0, c * 4);
        const int sb = min(t1, c * 4 + 4);
        for (int st = sa; st < sb; ++st) {
            const int kb32 = st << 5;

            // swapped QK^T: S^T[key][q]
            f32x4 sacc[2] = {};
            #pragma unroll
            for (int ds = 0; ds < 2; ++ds) {
                #pragma unroll
                for (int kt = 0; kt < 2; ++kt) {
                    const int krow = kb32 + kt * 16 + cc;
                    const int sl   = (ds * 4 + g) ^ (krow & 7);
                    const bf16x8 kfr = *(const bf16x8*)(Ks + krow * 64 + sl * 8);
                    sacc[kt] = __builtin_amdgcn_mfma_f32_16x16x32_bf16(kfr, qf[ds], sacc[kt], 0, 0, 0);
                }
            }

            // mask + exp + P write (per-wave LDS, wave-internal sync only)
            const int q = qlo + cc;
            #pragma unroll
            for (int kt = 0; kt < 2; ++kt) {
                float w4[4];
                const int keyb = kstart + kb32 + kt * 16 + g * 4;
                #pragma unroll
                for (int r = 0; r < 4; ++r) {
                    const int key = keyb + r;
                    const float e = __expf(fminf(sacc[kt][r], 60.f));
                    const int dd  = key - q;
                    const bool ok = (dd >= -HALF) && (dd <= HALF) && (key < S_LEN);
                    w4[r] = ok ? e : 0.f;
                    denom += w4[r];
                }
                *(uint2*)(Pw + cc * 40 + kt * 16 + g * 4) =
                    make_uint2(pk2(w4[0], w4[1]), pk2(w4[2], w4[3]));
            }

            // PV: O^T += V^T x P^T
            const bf16x8 pf = *(const bf16x8*)(Pw + cc * 40 + g * 8);
            #pragma unroll
            for (int dt = 0; dt < 4; ++dt) {
                const int d  = dt * 16 + cc;
                const int sl = ((kb32 >> 3) + g) ^ (d & 7);
                const bf16x8 vf = *(const bf16x8*)(Vs + d * KCAP + sl * 8);
                oacc[dt] = __builtin_amdgcn_mfma_f32_16x16x32_bf16(vf, pf, oacc[dt], 0, 0, 0);
            }
        }

        // 3) convert + LDS-write the prefetched chunk, then sync
        if (more) {
            k_write(c + 1, ka, kb);
            v_write(c + 1, vr);
            __syncthreads();
        }
    }

    // ---- normalize + store ----
    denom += __shfl_xor(denom, 16);
    denom += __shfl_xor(denom, 32);
    const float rinv = 1.f / denom;
    float* dst = Og + (size_t)(qlo + cc) * DIM;
    #pragma unroll
    for (int dt = 0; dt < 4; ++dt) {
        const f32x4 o = oacc[dt];
        *(float4*)(dst + dt * 16 + g * 4) =
            make_float4(o[0] * rinv, o[1] * rinv, o[2] * rinv, o[3] * rinv);
    }
}

extern "C" void kernel_launch(void* const* d_in, const int* in_sizes, int n_in,
                              void* d_out, int out_size, void* d_ws, size_t ws_size,
                              hipStream_t stream) {
    const float* q = (const float*)d_in[0];
    const float* k = (const float*)d_in[1];
    const float* v = (const float*)d_in[2];
    float* o = (float*)d_out;
    const int nbh = in_sizes[0] / (S_LEN * DIM);      // B*H = 16
    dim3 grid((S_LEN / RB) * nbh);                    // 256 blocks
    lattn_mfma<<<grid, THREADS, 0, stream>>>(q, k, v, o);
}